// Round 5
// baseline (451.508 us; speedup 1.0000x reference)
//
#include <hip/hip_runtime.h>

typedef unsigned short u16;
typedef short bf16x8 __attribute__((ext_vector_type(8)));
typedef float f32x4 __attribute__((ext_vector_type(4)));
typedef unsigned short u16x4 __attribute__((ext_vector_type(4)));

// B=2, T=2048, D=2048, H=16, dk=128, BH=32, M=B*T=4096, QKV cols=6144
#define QK_SCALE 0.08838834764831845f

__device__ __forceinline__ u16 f2bf(float f) {
  unsigned u = __float_as_uint(f);
  u += 0x7fffu + ((u >> 16) & 1u);
  return (u16)(u >> 16);
}
__device__ __forceinline__ float bf2f(u16 h) { return __uint_as_float(((unsigned)h) << 16); }

__device__ __forceinline__ void gld_lds16(const u16* g, u16* l) {
  __builtin_amdgcn_global_load_lds(
      (const __attribute__((address_space(1))) void*)g,
      (__attribute__((address_space(3))) void*)l, 16, 0, 0);
}

// ---------------- f32 -> bf16 convert ----------------
__global__ void cvt_bf16_kernel(const float* __restrict__ in, u16* __restrict__ out, int n4) {
  int i = blockIdx.x * 256 + threadIdx.x;
  if (i >= n4) return;
  const float4 v = reinterpret_cast<const float4*>(in)[i];
  u16x4 o;
  o[0] = f2bf(v.x); o[1] = f2bf(v.y); o[2] = f2bf(v.z); o[3] = f2bf(v.w);
  reinterpret_cast<u16x4*>(out)[i] = o;
}

// ---------------- rotary folded into Q/K weight rows (bug-faithful: angle = h*freqs[j]) --------
__global__ void rotw_kernel(const float* __restrict__ w, u16* __restrict__ wb) {
  const int i = blockIdx.x * 256 + threadIdx.x;   // which(2)*h(16)*j(64)*k4(512)
  const int k4 = i & 511;
  const int j = (i >> 9) & 63;
  const int h = (i >> 15) & 15;
  const int which = i >> 19;                       // 0=Q, 1=K
  const size_t e1 = (size_t)which * 2048 + h * 128 + j;
  const size_t e2 = e1 + 64;
  const float fr = (j < 32) ? __expf(-0.2971077539f * (float)j) : 0.0f;  // (1e-4)^(j/31)
  float s, c;
  __sincosf((float)h * fr, &s, &c);
  const float scale = (which == 0) ? QK_SCALE : 1.0f;
  const float4 a = reinterpret_cast<const float4*>(w + e1 * 2048)[k4];
  const float4 b = reinterpret_cast<const float4*>(w + e2 * 2048)[k4];
  u16x4 o1, o2;
  o1[0] = f2bf((a.x * c + b.x * s) * scale);
  o1[1] = f2bf((a.y * c + b.y * s) * scale);
  o1[2] = f2bf((a.z * c + b.z * s) * scale);
  o1[3] = f2bf((a.w * c + b.w * s) * scale);
  o2[0] = f2bf((b.x * c - a.x * s) * scale);
  o2[1] = f2bf((b.y * c - a.y * s) * scale);
  o2[2] = f2bf((b.z * c - a.z * s) * scale);
  o2[3] = f2bf((b.w * c - a.w * s) * scale);
  reinterpret_cast<u16x4*>(wb + e1 * 2048)[k4] = o1;
  reinterpret_cast<u16x4*>(wb + e2 * 2048)[k4] = o2;
}

// ================= 256x256 8-phase GEMM, one-phase read-ahead (m201 schedule) =================
// 512 thr = 8 waves (2Mx4N), BK=64, 2 K-tiles/iter, 8 phases/iter.
// Per phase: [1 half-tile stage] [4-or-8 ds_read_b128 for NEXT phase's MFMA]
//            [vmcnt(2) at ph3/ph7 only] barrier; lgkmcnt(0); setprio+16 MFMA; barrier.
// Hazards verified: buf0 reads end ph3 (staged ph3-6, drained ph7);
//                   buf1 reads end ph7 (staged ph7,8,1,2, drained ph3).
// MODE 0: bf16 row-major out ; MODE 1: f32 row-major out
template<int MODE>
__global__ __launch_bounds__(512, 2) void gemm8p_kernel(
    const u16* __restrict__ A, const u16* __restrict__ Bw, int Kdim, int n_out,
    u16* __restrict__ c_bf16, float* __restrict__ c_f32)
{
  __shared__ __align__(16) u16 As[2][256 * 64];
  __shared__ __align__(16) u16 Bs[2][256 * 64];
  const int t = threadIdx.x, lane = t & 63, w = t >> 6;
  const int wr = w >> 2, wc = w & 3;
  const int l15 = lane & 15, lhi = lane >> 4;
  const int m0 = blockIdx.x * 256, n0 = blockIdx.y * 256;
  const int NT = Kdim >> 6, NI = NT >> 1;

  // staging: each gld issue = 512 lanes x 16B = 64 rows; LDS linear, global pre-swizzled
  const int srow = w * 8 + (lane >> 3);
  const size_t gcol = (size_t)(((lane & 7) ^ (srow & 7)) * 8);

#define STA(buf, kt, h) { \
    const size_t kb_ = (size_t)(kt) * 64 + gcol; \
    gld_lds16(A + (size_t)(m0 + srow + (h) * 128) * Kdim + kb_, &As[buf][(w * 8 + (h) * 128) * 64]); \
    gld_lds16(A + (size_t)(m0 + srow + (h) * 128 + 64) * Kdim + kb_, &As[buf][(w * 8 + (h) * 128 + 64) * 64]); }
#define STB(buf, kt, h) { \
    const size_t kb_ = (size_t)(kt) * 64 + gcol; \
    gld_lds16(Bw + (size_t)(n0 + srow + (h) * 128) * Kdim + kb_, &Bs[buf][(w * 8 + (h) * 128) * 64]); \
    gld_lds16(Bw + (size_t)(n0 + srow + (h) * 128 + 64) * Kdim + kb_, &Bs[buf][(w * 8 + (h) * 128 + 64) * 64]); }

  const int arow = (wr * 128 + l15) * 64;
  const int brow = (wc * 64 + l15) * 64;
  const int ko0 = (lhi ^ (l15 & 7)) * 8;
  const int ko1 = ((4 + lhi) ^ (l15 & 7)) * 8;

#define RDA(buf, mq, ko, dst) { _Pragma("unroll") \
    for (int m_ = 0; m_ < 4; ++m_) dst[m_] = *reinterpret_cast<const bf16x8*>(&As[buf][arow + ((mq) + m_) * 1024 + (ko)]); }
#define RDB(buf, ko, dst) { _Pragma("unroll") \
    for (int n_ = 0; n_ < 4; ++n_) dst[n_] = *reinterpret_cast<const bf16x8*>(&Bs[buf][brow + n_ * 1024 + (ko)]); }
#define MMA(a_, b_, mq) { __builtin_amdgcn_s_setprio(1); _Pragma("unroll") \
    for (int m_ = 0; m_ < 4; ++m_) { _Pragma("unroll") for (int n_ = 0; n_ < 4; ++n_) \
      acc[(mq) + m_][n_] = __builtin_amdgcn_mfma_f32_16x16x32_bf16(a_[m_], b_[n_], acc[(mq) + m_][n_], 0, 0, 0); } \
    __builtin_amdgcn_s_setprio(0); }
#define BAR() __builtin_amdgcn_s_barrier()
#define LGK0() asm volatile("s_waitcnt lgkmcnt(0)" ::: "memory")

  f32x4 acc[8][4];
#pragma unroll
  for (int m = 0; m < 8; ++m)
#pragma unroll
    for (int n = 0; n < 4; ++n)
#pragma unroll
      for (int i = 0; i < 4; ++i) acc[m][n][i] = 0.0f;

  bf16x8 aq[4], aqn[4], b0[4], b1[4];

  // prologue: buf0 full (tile 0), buf1 units Bh0+Ah0 (tile 1); drain buf0; first Q1 reads
  STB(0, 0, 0); STA(0, 0, 0); STA(0, 0, 1); STB(0, 0, 1);
  STB(1, 1, 0); STA(1, 1, 0);
  asm volatile("s_waitcnt vmcnt(4)" ::: "memory");
  BAR();
  RDA(0, 0, ko0, aq); RDB(0, ko0, b0);

  for (int i = 0; i < NI; ++i) {
    const int t1 = 2 * i + 1;
    const bool g = (i + 1 < NI);
    // ph1: stage b1.Ah1(t1); read Q2(t0); MFMA Q1(t0)
    STA(1, t1, 1);
    RDA(0, 4, ko0, aqn);
    BAR(); LGK0(); MMA(aq, b0, 0); BAR();
    // ph2: stage b1.Bh1(t1); read Q3(t0); MFMA Q2(t0)
    STB(1, t1, 1);
    RDA(0, 0, ko1, aq); RDB(0, ko1, b1);
    BAR(); LGK0(); MMA(aqn, b0, 4); BAR();
    // ph3: stage b0.Bh0(t0+2); read Q4(t0); vmcnt drains buf1-units; MFMA Q3(t0)
    if (g) { STB(0, t1 + 1, 0); }
    RDA(0, 4, ko1, aqn);
    if (g) { asm volatile("s_waitcnt vmcnt(2)" ::: "memory"); }
    else   { asm volatile("s_waitcnt vmcnt(0)" ::: "memory"); }
    BAR(); LGK0(); MMA(aq, b1, 0); BAR();
    // ph4: stage b0.Ah0(t0+2); read Q1(t1) from buf1; MFMA Q4(t0)
    if (g) { STA(0, t1 + 1, 0); }
    RDA(1, 0, ko0, aq); RDB(1, ko0, b0);
    BAR(); LGK0(); MMA(aqn, b1, 4); BAR();
    // ph5: stage b0.Ah1(t0+2); read Q2(t1); MFMA Q1(t1)
    if (g) { STA(0, t1 + 1, 1); }
    RDA(1, 4, ko0, aqn);
    BAR(); LGK0(); MMA(aq, b0, 0); BAR();
    // ph6: stage b0.Bh1(t0+2); read Q3(t1); MFMA Q2(t1)
    if (g) { STB(0, t1 + 1, 1); }
    RDA(1, 0, ko1, aq); RDB(1, ko1, b1);
    BAR(); LGK0(); MMA(aqn, b0, 4); BAR();
    // ph7: stage b1.Bh0(t1+2); read Q4(t1); vmcnt drains buf0-units; MFMA Q3(t1)
    if (g) { STB(1, t1 + 2, 0); }
    RDA(1, 4, ko1, aqn);
    if (g) { asm volatile("s_waitcnt vmcnt(2)" ::: "memory"); }
    else   { asm volatile("s_waitcnt vmcnt(0)" ::: "memory"); }
    BAR(); LGK0(); MMA(aq, b1, 0); BAR();
    // ph8: stage b1.Ah0(t1+2); read Q1(t0+2) from buf0; MFMA Q4(t1)
    if (g) { STA(1, t1 + 2, 0); }
    if (g) { RDA(0, 0, ko0, aq); RDB(0, ko0, b0); }
    BAR(); LGK0(); MMA(aqn, b1, 4); BAR();
  }

  // epilogue: row = m0 + wr*128 + m*16 + lhi*4 + r ; col = n0 + wc*64 + n*16 + l15
  const int rb = wr * 128 + lhi * 4;
  const int cb = wc * 64 + l15;
#pragma unroll
  for (int m = 0; m < 8; ++m)
#pragma unroll
    for (int r = 0; r < 4; ++r) {
      const size_t row = (size_t)(m0 + rb + m * 16 + r);
      if (MODE == 0) {
#pragma unroll
        for (int n = 0; n < 4; ++n)
          c_bf16[row * n_out + n0 + cb + n * 16] = f2bf(acc[m][n][r]);
      } else {
#pragma unroll
        for (int n = 0; n < 4; ++n)
          c_f32[row * n_out + n0 + cb + n * 16] = acc[m][n][r];
      }
    }
#undef STA
#undef STB
#undef RDA
#undef RDB
#undef MMA
#undef BAR
#undef LGK0
}

// ---------------- m97-structure 128x128 GEMM (out-projection) ----------------
__global__ __launch_bounds__(256) void gemm_bt_kernel(
    const u16* __restrict__ A, const u16* __restrict__ Bw, int Kdim, int n_out,
    float* __restrict__ f_out)
{
  __shared__ __align__(16) u16 Asl[128 * 32];
  __shared__ __align__(16) u16 Bsl[128 * 32];
  const int t = threadIdx.x;
  const int lane = t & 63;
  const int w = t >> 6;
  const int wr = w >> 1, wc = w & 1;
  const int m0 = blockIdx.x * 128, n0 = blockIdx.y * 128;

  f32x4 acc[4][4];
#pragma unroll
  for (int m = 0; m < 4; ++m)
#pragma unroll
    for (int n = 0; n < 4; ++n)
#pragma unroll
      for (int i = 0; i < 4; ++i) acc[m][n][i] = 0.0f;

  const int ob0 = w * 1024 + lane * 16;
  const int row0 = ob0 >> 6;
  const int cole0 = (ob0 & 63) >> 1;
  const u16* gA0 = A + (size_t)(m0 + row0) * Kdim + cole0;
  const u16* gA1 = gA0 + (size_t)64 * Kdim;
  const u16* gB0 = Bw + (size_t)(n0 + row0) * Kdim + cole0;
  const u16* gB1 = gB0 + (size_t)64 * Kdim;
  u16* lA = Asl + w * 512;
  u16* lB = Bsl + w * 512;

  const int l15 = lane & 15;
  const int kb = (lane >> 4) * 8;

  for (int k0 = 0; k0 < Kdim; k0 += 32) {
    __syncthreads();
    gld_lds16(gA0, lA);
    gld_lds16(gA1, lA + 2048);
    gld_lds16(gB0, lB);
    gld_lds16(gB1, lB + 2048);
    gA0 += 32; gA1 += 32; gB0 += 32; gB1 += 32;
    __syncthreads();
    bf16x8 a[4], b[4];
#pragma unroll
    for (int m = 0; m < 4; ++m)
      a[m] = *reinterpret_cast<const bf16x8*>(Asl + (wr * 64 + m * 16 + l15) * 32 + kb);
#pragma unroll
    for (int n = 0; n < 4; ++n)
      b[n] = *reinterpret_cast<const bf16x8*>(Bsl + (wc * 64 + n * 16 + l15) * 32 + kb);
#pragma unroll
    for (int m = 0; m < 4; ++m)
#pragma unroll
      for (int n = 0; n < 4; ++n)
        acc[m][n] = __builtin_amdgcn_mfma_f32_16x16x32_bf16(a[m], b[n], acc[m][n], 0, 0, 0);
  }

  const int rb = wr * 64 + ((lane >> 4) << 2);
  const int cbs = wc * 64 + l15;
#pragma unroll
  for (int m = 0; m < 4; ++m)
#pragma unroll
    for (int r = 0; r < 4; ++r) {
      const int row = m0 + rb + m * 16 + r;
#pragma unroll
      for (int n = 0; n < 4; ++n)
        f_out[(size_t)row * n_out + n0 + cbs + n * 16] = acc[m][n][r];
    }
}

// ---------------- V transpose from QKV buffer: (bt, 4096+h*128+d) -> Vt (bh, d, t) ----------------
__global__ void transpose_v_kernel(const u16* __restrict__ QKV, u16* __restrict__ Vt) {
  __shared__ u16 tile[64][65];
  const int d0 = blockIdx.x * 64;
  const int t0 = blockIdx.y * 64;
  const int bh = blockIdx.z;
  const int bb = bh >> 4, h = bh & 15;
  const u16* src = QKV + (size_t)(bb * 2048) * 6144 + 4096 + h * 128;
  u16* dst = Vt + (size_t)bh * (128 * 2048);
  const int tid = threadIdx.x;
  const int c4 = (tid & 15) * 4;
  const int r0 = tid >> 4;
#pragma unroll
  for (int p = 0; p < 4; ++p) {
    const int row = r0 + p * 16;
    const u16x4 v = *reinterpret_cast<const u16x4*>(src + (size_t)(t0 + row) * 6144 + d0 + c4);
    tile[row][c4] = v[0]; tile[row][c4 + 1] = v[1];
    tile[row][c4 + 2] = v[2]; tile[row][c4 + 3] = v[3];
  }
  __syncthreads();
#pragma unroll
  for (int p = 0; p < 4; ++p) {
    const int dr = r0 + p * 16;
    u16x4 ov;
    ov[0] = tile[c4][dr]; ov[1] = tile[c4 + 1][dr];
    ov[2] = tile[c4 + 2][dr]; ov[3] = tile[c4 + 3][dr];
    *reinterpret_cast<u16x4*>(dst + (size_t)(d0 + dr) * 2048 + t0 + c4) = ov;
  }
}

// ---------------- flash attention, LDS-staged K/V, double-buffered, load-balanced ----------------
// Q/K read from row-major QKV (stride 6144); V from Vt (bh,d,t).
__global__ __launch_bounds__(256) void attn_kernel(
    const u16* __restrict__ QKV, const u16* __restrict__ Vt, u16* __restrict__ O)
{
  __shared__ __align__(16) u16 k_lds[2][64 * 128];
  __shared__ __align__(16) u16 v_lds[2][128 * 64];
  __shared__ __align__(16) u16 p_lds[4][1024];
  const int t = threadIdx.x, lane = t & 63, w = t >> 6;
  const int bh = blockIdx.y;
  const int bx = blockIdx.x;
  const int l15 = lane & 15, lhi = lane >> 4;
  const int bb = bh >> 4, h = bh & 15;
  const u16* Qg = QKV + (size_t)(bb * 2048) * 6144 + h * 128;           // row stride 6144
  const u16* Kg = QKV + (size_t)(bb * 2048) * 6144 + 2048 + h * 128;    // row stride 6144
  const u16* Vg = Vt + (size_t)bh * (size_t)(128 * 2048);
  char* pw = (char*)(&p_lds[w][0]);
  const int kxor = (l15 & 7) << 4;

  auto stage = [&](int buf, int k0) {
#pragma unroll
    for (int ii = 0; ii < 4; ++ii) {
      const int i = w * 4 + ii;
      const int krow = i * 4 + lhi;
      gld_lds16(Kg + (size_t)(k0 + krow) * 6144 + (size_t)((l15 ^ (krow & 7)) * 8),
                &k_lds[buf][i * 512]);
    }
#pragma unroll
    for (int ii = 0; ii < 4; ++ii) {
      const int i = w * 4 + ii;
      const int vrow = i * 8 + (lane >> 3);
      gld_lds16(Vg + (size_t)vrow * 2048 + k0 + (size_t)(((lane & 7) ^ (vrow & 7)) * 8),
                &v_lds[buf][i * 512]);
    }
  };

  for (int half = 0; half < 2; ++half) {
    const int qt = half ? (31 - bx) : bx;
    const int q0 = qt * 64 + w * 16;
    bf16x8 aq[4];
    {
      const u16* qp = Qg + (size_t)(q0 + l15) * 6144 + lhi * 8;
#pragma unroll
      for (int ks = 0; ks < 4; ++ks) aq[ks] = *reinterpret_cast<const bf16x8*>(qp + ks * 32);
    }
    f32x4 o[8];
#pragma unroll
    for (int dt = 0; dt < 8; ++dt)
#pragma unroll
      for (int i = 0; i < 4; ++i) o[dt][i] = 0.0f;
    float mrow[4] = {-1e30f, -1e30f, -1e30f, -1e30f};
    float lrow[4] = {0.f, 0.f, 0.f, 0.f};
    const int rbase = q0 + (lhi << 2);
    const int ktmax = qt;

    __syncthreads();
    stage(0, 0);
    int cur = 0;
    for (int kt = 0; kt <= ktmax; ++kt) {
      __syncthreads();
      if (kt < ktmax) stage(cur ^ 1, (kt + 1) * 64);

      const char* kbb = (const char*)(&k_lds[cur][0]);
      f32x4 s4[4];
#pragma unroll
      for (int nt = 0; nt < 4; ++nt)
#pragma unroll
        for (int i = 0; i < 4; ++i) s4[nt][i] = 0.0f;
#pragma unroll
      for (int nt = 0; nt < 4; ++nt) {
        const int krow = nt * 16 + l15;
#pragma unroll
        for (int ks = 0; ks < 4; ++ks) {
          const bf16x8 bk = *reinterpret_cast<const bf16x8*>(
              kbb + krow * 256 + ((ks * 64 + lhi * 16) ^ kxor));
          s4[nt] = __builtin_amdgcn_mfma_f32_16x16x32_bf16(aq[ks], bk, s4[nt], 0, 0, 0);
        }
      }
      if (kt == ktmax) {
#pragma unroll
        for (int nt = 0; nt < 4; ++nt) {
          const int col = kt * 64 + nt * 16 + l15;
#pragma unroll
          for (int r = 0; r < 4; ++r)
            if (col > rbase + r) s4[nt][r] = -1e30f;
        }
      }
      float alpha[4];
#pragma unroll
      for (int r = 0; r < 4; ++r) {
        float mx = fmaxf(fmaxf(s4[0][r], s4[1][r]), fmaxf(s4[2][r], s4[3][r]));
        mx = fmaxf(mx, __shfl_xor(mx, 1));
        mx = fmaxf(mx, __shfl_xor(mx, 2));
        mx = fmaxf(mx, __shfl_xor(mx, 4));
        mx = fmaxf(mx, __shfl_xor(mx, 8));
        const float mn = fmaxf(mrow[r], mx);
        alpha[r] = __expf(mrow[r] - mn);
        mrow[r] = mn;
      }
      float ps[4] = {0.f, 0.f, 0.f, 0.f};
#pragma unroll
      for (int nt = 0; nt < 4; ++nt)
#pragma unroll
        for (int r = 0; r < 4; ++r) {
          const float p = __expf(s4[nt][r] - mrow[r]);
          ps[r] += p;
          const int prow = (lhi << 2) + r;
          const int cbyte = (nt * 16 + l15) * 2;
          *(u16*)(pw + prow * 128 + (cbyte ^ ((prow & 7) << 4))) = f2bf(p);
        }
#pragma unroll
      for (int r = 0; r < 4; ++r) {
        float rs = ps[r];
        rs += __shfl_xor(rs, 1);
        rs += __shfl_xor(rs, 2);
        rs += __shfl_xor(rs, 4);
        rs += __shfl_xor(rs, 8);
        lrow[r] = lrow[r] * alpha[r] + rs;
#pragma unroll
        for (int dt = 0; dt < 8; ++dt) o[dt][r] *= alpha[r];
      }
      const char* vbb = (const char*)(&v_lds[cur][0]);
#pragma unroll
      for (int ks2 = 0; ks2 < 2; ++ks2) {
        const bf16x8 ap = *reinterpret_cast<const bf16x8*>(
            pw + l15 * 128 + ((ks2 * 64 + (lhi << 4)) ^ kxor));
#pragma unroll
        for (int dt = 0; dt < 8; ++dt) {
          const int vrow = dt * 16 + l15;
          const bf16x8 bv = *reinterpret_cast<const bf16x8*>(
              vbb + vrow * 128 + ((ks2 * 64 + lhi * 16) ^ kxor));
          o[dt] = __builtin_amdgcn_mfma_f32_16x16x32_bf16(ap, bv, o[dt], 0, 0, 0);
        }
      }
      cur ^= 1;
    }
#pragma unroll
    for (int r = 0; r < 4; ++r) {
      const float inv = 1.0f / lrow[r];
      const int row = rbase + r;
      u16* op = O + (size_t)(bb * 2048 + row) * 2048 + h * 128 + l15;
#pragma unroll
      for (int dt = 0; dt < 8; ++dt) op[dt * 16] = f2bf(o[dt][r] * inv);
    }
  }
}

extern "C" void kernel_launch(void* const* d_in, const int* in_sizes, int n_in,
                              void* d_out, int out_size, void* d_ws, size_t ws_size,
                              hipStream_t stream) {
  const float* x = (const float*)d_in[0];      // (2,2048,2048) f32
  const float* wqkv = (const float*)d_in[1];   // (6144,2048) f32
  const float* wo = (const float*)d_in[2];     // (2048,2048) f32
  float* out = (float*)d_out;                  // (2,2048,2048) f32
  u16* ws = (u16*)d_ws;

  u16* xb = ws;                    // 8,388,608 elems
  u16* wqkvb = xb + 8388608;       // 12,582,912 (rotary-folded Q/K rows + plain V rows)
  u16* wob = wqkvb + 12582912;     // 4,194,304
  u16* qkvb = wob + 4194304;       // 25,165,824 (4096 x 6144 bf16, row-major)
  u16* Vtb = wqkvb;                // alias: wqkvb dead after QKV GEMM (needs 8,388,608)
  u16* attn = xb;                  // alias: xb dead after QKV GEMM

  cvt_bf16_kernel<<<8192, 256, 0, stream>>>(x, xb, 2097152);
  rotw_kernel<<<4096, 256, 0, stream>>>(wqkv, wqkvb);
  cvt_bf16_kernel<<<4096, 256, 0, stream>>>(wqkv + (size_t)4096 * 2048,
                                            wqkvb + (size_t)4096 * 2048, 1048576);
  cvt_bf16_kernel<<<4096, 256, 0, stream>>>(wo, wob, 1048576);

  // QKV: M=4096, N=6144, K=2048 -> row-major bf16 qkvb (coalesced epilogue)
  gemm8p_kernel<0><<<dim3(16, 24), 512, 0, stream>>>(xb, wqkvb, 2048, 6144, qkvb, nullptr);

  transpose_v_kernel<<<dim3(2, 32, 32), 256, 0, stream>>>(qkvb, Vtb);

  attn_kernel<<<dim3(16, 32), 256, 0, stream>>>(qkvb, Vtb, attn);

  // Out proj: M=4096, N=2048, K=2048 -> f32 d_out
  gemm_bt_kernel<<<dim3(32, 16), 256, 0, stream>>>(attn, wob, 2048, 2048, out);
}

// Round 6
// 311.215 us; speedup vs baseline: 1.4508x; 1.4508x over previous
//
#include <hip/hip_runtime.h>

typedef unsigned short u16;
typedef short bf16x8 __attribute__((ext_vector_type(8)));
typedef float f32x4 __attribute__((ext_vector_type(4)));
typedef unsigned short u16x4 __attribute__((ext_vector_type(4)));

// B=2, T=2048, D=2048, H=16, dk=128, BH=32, M=B*T=4096
#define QK_SCALE 0.08838834764831845f

__device__ __forceinline__ u16 f2bf(float f) {
  unsigned u = __float_as_uint(f);
  u += 0x7fffu + ((u >> 16) & 1u);
  return (u16)(u >> 16);
}
__device__ __forceinline__ float bf2f(u16 h) { return __uint_as_float(((unsigned)h) << 16); }

__device__ __forceinline__ void gld_lds16(const u16* g, u16* l) {
  __builtin_amdgcn_global_load_lds(
      (const __attribute__((address_space(1))) void*)g,
      (__attribute__((address_space(3))) void*)l, 16, 0, 0);
}

// ---------------- f32 -> bf16 convert ----------------
__global__ void cvt_bf16_kernel(const float* __restrict__ in, u16* __restrict__ out, int n4) {
  int i = blockIdx.x * 256 + threadIdx.x;
  if (i >= n4) return;
  const float4 v = reinterpret_cast<const float4*>(in)[i];
  u16x4 o;
  o[0] = f2bf(v.x); o[1] = f2bf(v.y); o[2] = f2bf(v.z); o[3] = f2bf(v.w);
  reinterpret_cast<u16x4*>(out)[i] = o;
}

// ---------------- rotary folded into Q/K weight rows (bug-faithful: angle = h*freqs[j]) --------
// W'[e_j] = c*W[e_j] + s*W[e_j+64] ; W'[e_j+64] = -s*W[e_j] + c*W[e_j+64]  (x QK_SCALE for Q)
__global__ void rotw_kernel(const float* __restrict__ w, u16* __restrict__ wb) {
  const int i = blockIdx.x * 256 + threadIdx.x;   // which(2)*h(16)*j(64)*k4(512)
  const int k4 = i & 511;
  const int j = (i >> 9) & 63;
  const int h = (i >> 15) & 15;
  const int which = i >> 19;                       // 0=Q, 1=K
  const size_t e1 = (size_t)which * 2048 + h * 128 + j;
  const size_t e2 = e1 + 64;
  const float fr = (j < 32) ? __expf(-0.2971077539f * (float)j) : 0.0f;  // (1e-4)^(j/31)
  float s, c;
  __sincosf((float)h * fr, &s, &c);
  const float scale = (which == 0) ? QK_SCALE : 1.0f;
  const float4 a = reinterpret_cast<const float4*>(w + e1 * 2048)[k4];
  const float4 b = reinterpret_cast<const float4*>(w + e2 * 2048)[k4];
  u16x4 o1, o2;
  o1[0] = f2bf((a.x * c + b.x * s) * scale);
  o1[1] = f2bf((a.y * c + b.y * s) * scale);
  o1[2] = f2bf((a.z * c + b.z * s) * scale);
  o1[3] = f2bf((a.w * c + b.w * s) * scale);
  o2[0] = f2bf((b.x * c - a.x * s) * scale);
  o2[1] = f2bf((b.y * c - a.y * s) * scale);
  o2[2] = f2bf((b.z * c - a.z * s) * scale);
  o2[3] = f2bf((b.w * c - a.w * s) * scale);
  reinterpret_cast<u16x4*>(wb + e1 * 2048)[k4] = o1;
  reinterpret_cast<u16x4*>(wb + e2 * 2048)[k4] = o2;
}

// ================= 256x256 8-phase GEMM (round-3 proven config), C=A*Bw^T =================
// 512 thr = 8 waves (2Mx4N), BK=64, LDS 128KB dbuf, chunk-XOR swizzle both sides,
// counted vmcnt(4), raw s_barrier, setprio MFMA. Flat block order.
// MODE 0: scatter bf16 into Q/K/V (B,H,T,dk) row-major per head.
template<int MODE>
__global__ __launch_bounds__(512, 2) void gemm8p_kernel(
    const u16* __restrict__ A, const u16* __restrict__ Bw, int Kdim, int n_out,
    u16* __restrict__ q_out, u16* __restrict__ k_out, u16* __restrict__ v_out,
    float* __restrict__ f_out)
{
  __shared__ __align__(16) u16 As[2][256 * 64];
  __shared__ __align__(16) u16 Bs[2][256 * 64];
  const int t = threadIdx.x, lane = t & 63, w = t >> 6;
  const int wr = w >> 2, wc = w & 3;
  const int l15 = lane & 15, lhi = lane >> 4;
  const int m0 = blockIdx.x * 256, n0 = blockIdx.y * 256;
  const int NT = Kdim >> 6;

  const int srow = w * 8 + (lane >> 3);
  const int gchunk = (lane & 7) ^ (srow & 7);
  const size_t gcol = (size_t)gchunk * 8;

  auto stageA2 = [&](int buf, int kt2, int half) {
    const size_t kb = (size_t)kt2 * 64 + gcol;
#pragma unroll
    for (int i = 0; i < 2; ++i) {
      const int ro = half * 128 + i * 64;
      gld_lds16(A + (size_t)(m0 + srow + ro) * Kdim + kb, &As[buf][(w * 8 + ro) * 64]);
    }
  };
  auto stageB4 = [&](int buf, int kt2) {
    const size_t kb = (size_t)kt2 * 64 + gcol;
#pragma unroll
    for (int ro = 0; ro < 256; ro += 64)
      gld_lds16(Bw + (size_t)(n0 + srow + ro) * Kdim + kb, &Bs[buf][(w * 8 + ro) * 64]);
  };

  const int arow0 = (wr * 128 + l15) * 64;
  const int brow0 = (wc * 64 + l15) * 64;
  const int koff0 = ((0 + lhi) ^ (l15 & 7)) * 8;
  const int koff1 = ((4 + lhi) ^ (l15 & 7)) * 8;

  f32x4 acc[8][4];
#pragma unroll
  for (int m = 0; m < 8; ++m)
#pragma unroll
    for (int n = 0; n < 4; ++n)
#pragma unroll
      for (int i = 0; i < 4; ++i) acc[m][n][i] = 0.0f;

  stageA2(0, 0, 0); stageA2(0, 0, 1);
  stageB4(0, 0);
  if (NT > 1) { stageA2(1, 1, 0); stageA2(1, 1, 1); }
  asm volatile("s_waitcnt vmcnt(4)" ::: "memory");
  __builtin_amdgcn_s_barrier();

  for (int kt = 0; kt < NT; ++kt) {
    const int cur = kt & 1;
    const u16* __restrict__ Ac = &As[cur][0];
    const u16* __restrict__ Bc = &Bs[cur][0];
    bf16x8 aK1[4], a2K1[4], b0[4], b1[4];
    // P1: read A[m0-3] k0+k1, B k0; stage B(t+1); MFMA m0-3 x k0
    {
      bf16x8 aK0[4];
#pragma unroll
      for (int m = 0; m < 4; ++m) {
        aK0[m] = *reinterpret_cast<const bf16x8*>(Ac + arow0 + m * 1024 + koff0);
        aK1[m] = *reinterpret_cast<const bf16x8*>(Ac + arow0 + m * 1024 + koff1);
      }
#pragma unroll
      for (int n = 0; n < 4; ++n)
        b0[n] = *reinterpret_cast<const bf16x8*>(Bc + brow0 + n * 1024 + koff0);
      if (kt + 1 < NT) stageB4(cur ^ 1, kt + 1);
      __builtin_amdgcn_s_barrier();
      asm volatile("s_waitcnt lgkmcnt(0)" ::: "memory");
      __builtin_amdgcn_s_setprio(1);
#pragma unroll
      for (int m = 0; m < 4; ++m)
#pragma unroll
        for (int n = 0; n < 4; ++n)
          acc[m][n] = __builtin_amdgcn_mfma_f32_16x16x32_bf16(aK0[m], b0[n], acc[m][n], 0, 0, 0);
      __builtin_amdgcn_s_setprio(0);
      __builtin_amdgcn_s_barrier();
    }
    // P2: read A[m4-7] k0+k1, B k1; MFMA m4-7 x k0
    {
      bf16x8 a2K0[4];
#pragma unroll
      for (int m = 0; m < 4; ++m) {
        a2K0[m] = *reinterpret_cast<const bf16x8*>(Ac + arow0 + (m + 4) * 1024 + koff0);
        a2K1[m] = *reinterpret_cast<const bf16x8*>(Ac + arow0 + (m + 4) * 1024 + koff1);
      }
#pragma unroll
      for (int n = 0; n < 4; ++n)
        b1[n] = *reinterpret_cast<const bf16x8*>(Bc + brow0 + n * 1024 + koff1);
      __builtin_amdgcn_s_barrier();
      asm volatile("s_waitcnt lgkmcnt(0)" ::: "memory");
      __builtin_amdgcn_s_setprio(1);
#pragma unroll
      for (int m = 0; m < 4; ++m)
#pragma unroll
        for (int n = 0; n < 4; ++n)
          acc[m + 4][n] = __builtin_amdgcn_mfma_f32_16x16x32_bf16(a2K0[m], b0[n], acc[m + 4][n], 0, 0, 0);
      __builtin_amdgcn_s_setprio(0);
      __builtin_amdgcn_s_barrier();
    }
    // P3: stage A(t+2) half0; MFMA m0-3 x k1
    if (kt + 2 < NT) stageA2(cur, kt + 2, 0);
    __builtin_amdgcn_s_barrier();
    __builtin_amdgcn_s_setprio(1);
#pragma unroll
    for (int m = 0; m < 4; ++m)
#pragma unroll
      for (int n = 0; n < 4; ++n)
        acc[m][n] = __builtin_amdgcn_mfma_f32_16x16x32_bf16(aK1[m], b1[n], acc[m][n], 0, 0, 0);
    __builtin_amdgcn_s_setprio(0);
    __builtin_amdgcn_s_barrier();
    // P4: stage A(t+2) half1; MFMA m4-7 x k1; counted vmcnt
    if (kt + 2 < NT) stageA2(cur, kt + 2, 1);
    __builtin_amdgcn_s_barrier();
    __builtin_amdgcn_s_setprio(1);
#pragma unroll
    for (int m = 0; m < 4; ++m)
#pragma unroll
      for (int n = 0; n < 4; ++n)
        acc[m + 4][n] = __builtin_amdgcn_mfma_f32_16x16x32_bf16(a2K1[m], b1[n], acc[m + 4][n], 0, 0, 0);
    __builtin_amdgcn_s_setprio(0);
    if (kt < NT - 2) { asm volatile("s_waitcnt vmcnt(4)" ::: "memory"); }
    else             { asm volatile("s_waitcnt vmcnt(0)" ::: "memory"); }
    __builtin_amdgcn_s_barrier();
  }

  // epilogue: row = m0 + wr*128 + m*16 + lhi*4 + r ; col = n0 + wc*64 + n*16 + l15
  const int rb = wr * 128 + lhi * 4;
  const int cb = wc * 64 + l15;
  if (MODE == 0) {
#pragma unroll
    for (int n = 0; n < 4; ++n) {
      const int e = n0 + cb + n * 16;
      const int which = e >> 11;
      const int h = (e >> 7) & 15;
      const int d = e & 127;
      u16* dst = (which == 0) ? q_out : (which == 1) ? k_out : v_out;
#pragma unroll
      for (int m = 0; m < 8; ++m)
#pragma unroll
        for (int r = 0; r < 4; ++r) {
          const int bt = m0 + rb + m * 16 + r;
          const int bb = bt >> 11, tt = bt & 2047;
          dst[((size_t)(bb * 16 + h) * 2048 + tt) * 128 + d] = f2bf(acc[m][n][r]);
        }
    }
  } else {
#pragma unroll
    for (int m = 0; m < 8; ++m)
#pragma unroll
      for (int r = 0; r < 4; ++r) {
        const int row = m0 + rb + m * 16 + r;
#pragma unroll
        for (int n = 0; n < 4; ++n)
          f_out[(size_t)row * n_out + n0 + cb + n * 16] = acc[m][n][r];
      }
  }
}

// ---------------- m97-structure 128x128 GEMM (out-projection) ----------------
__global__ __launch_bounds__(256) void gemm_bt_kernel(
    const u16* __restrict__ A, const u16* __restrict__ Bw, int Kdim, int n_out,
    float* __restrict__ f_out)
{
  __shared__ __align__(16) u16 Asl[128 * 32];
  __shared__ __align__(16) u16 Bsl[128 * 32];
  const int t = threadIdx.x;
  const int lane = t & 63;
  const int w = t >> 6;
  const int wr = w >> 1, wc = w & 1;
  const int m0 = blockIdx.x * 128, n0 = blockIdx.y * 128;

  f32x4 acc[4][4];
#pragma unroll
  for (int m = 0; m < 4; ++m)
#pragma unroll
    for (int n = 0; n < 4; ++n)
#pragma unroll
      for (int i = 0; i < 4; ++i) acc[m][n][i] = 0.0f;

  const int ob0 = w * 1024 + lane * 16;
  const int row0 = ob0 >> 6;
  const int cole0 = (ob0 & 63) >> 1;
  const u16* gA0 = A + (size_t)(m0 + row0) * Kdim + cole0;
  const u16* gA1 = gA0 + (size_t)64 * Kdim;
  const u16* gB0 = Bw + (size_t)(n0 + row0) * Kdim + cole0;
  const u16* gB1 = gB0 + (size_t)64 * Kdim;
  u16* lA = Asl + w * 512;
  u16* lB = Bsl + w * 512;

  const int l15 = lane & 15;
  const int kb = (lane >> 4) * 8;

  for (int k0 = 0; k0 < Kdim; k0 += 32) {
    __syncthreads();
    gld_lds16(gA0, lA);
    gld_lds16(gA1, lA + 2048);
    gld_lds16(gB0, lB);
    gld_lds16(gB1, lB + 2048);
    gA0 += 32; gA1 += 32; gB0 += 32; gB1 += 32;
    __syncthreads();
    bf16x8 a[4], b[4];
#pragma unroll
    for (int m = 0; m < 4; ++m)
      a[m] = *reinterpret_cast<const bf16x8*>(Asl + (wr * 64 + m * 16 + l15) * 32 + kb);
#pragma unroll
    for (int n = 0; n < 4; ++n)
      b[n] = *reinterpret_cast<const bf16x8*>(Bsl + (wc * 64 + n * 16 + l15) * 32 + kb);
#pragma unroll
    for (int m = 0; m < 4; ++m)
#pragma unroll
      for (int n = 0; n < 4; ++n)
        acc[m][n] = __builtin_amdgcn_mfma_f32_16x16x32_bf16(a[m], b[n], acc[m][n], 0, 0, 0);
  }

  const int rb = wr * 64 + ((lane >> 4) << 2);
  const int cbs = wc * 64 + l15;
#pragma unroll
  for (int m = 0; m < 4; ++m)
#pragma unroll
    for (int r = 0; r < 4; ++r) {
      const int row = m0 + rb + m * 16 + r;
#pragma unroll
      for (int n = 0; n < 4; ++n)
        f_out[(size_t)row * n_out + n0 + cbs + n * 16] = acc[m][n][r];
    }
}

// ---------------- V transpose: (bh, t, d) -> (bh, d, t) ----------------
__global__ void transpose_v_kernel(const u16* __restrict__ V, u16* __restrict__ Vt) {
  __shared__ u16 tile[64][65];
  const int d0 = blockIdx.x * 64;
  const int t0 = blockIdx.y * 64;
  const int bh = blockIdx.z;
  const u16* src = V + (size_t)bh * (2048 * 128);
  u16* dst = Vt + (size_t)bh * (128 * 2048);
  const int tid = threadIdx.x;
  const int c4 = (tid & 15) * 4;
  const int r0 = tid >> 4;
#pragma unroll
  for (int p = 0; p < 4; ++p) {
    const int row = r0 + p * 16;
    const u16x4 v = *reinterpret_cast<const u16x4*>(src + (size_t)(t0 + row) * 128 + d0 + c4);
    tile[row][c4] = v[0]; tile[row][c4 + 1] = v[1];
    tile[row][c4 + 2] = v[2]; tile[row][c4 + 3] = v[3];
  }
  __syncthreads();
#pragma unroll
  for (int p = 0; p < 4; ++p) {
    const int dr = r0 + p * 16;
    u16x4 ov;
    ov[0] = tile[c4][dr]; ov[1] = tile[c4 + 1][dr];
    ov[2] = tile[c4 + 2][dr]; ov[3] = tile[c4 + 3][dr];
    *reinterpret_cast<u16x4*>(dst + (size_t)(d0 + dr) * 2048 + t0 + c4) = ov;
  }
}

// ---------------- flash attention, LDS-staged K/V, double-buffered, load-balanced ----------------
__global__ __launch_bounds__(256) void attn_kernel(
    const u16* __restrict__ Q, const u16* __restrict__ K,
    const u16* __restrict__ Vt, u16* __restrict__ O)
{
  __shared__ __align__(16) u16 k_lds[2][64 * 128];
  __shared__ __align__(16) u16 v_lds[2][128 * 64];
  __shared__ __align__(16) u16 p_lds[4][1024];
  const int t = threadIdx.x, lane = t & 63, w = t >> 6;
  const int bh = blockIdx.y;
  const int bx = blockIdx.x;
  const int l15 = lane & 15, lhi = lane >> 4;
  const size_t qkb = (size_t)bh * (2048 * 128);
  const u16* Kg = K + qkb;
  const u16* Vg = Vt + (size_t)bh * (size_t)(128 * 2048);
  char* pw = (char*)(&p_lds[w][0]);
  const int bb = bh >> 4, h = bh & 15;
  const int kxor = (l15 & 7) << 4;

  auto stage = [&](int buf, int k0) {
#pragma unroll
    for (int ii = 0; ii < 4; ++ii) {
      const int i = w * 4 + ii;
      const int krow = i * 4 + lhi;
      gld_lds16(Kg + (size_t)(k0 + krow) * 128 + (size_t)((l15 ^ (krow & 7)) * 8),
                &k_lds[buf][i * 512]);
    }
#pragma unroll
    for (int ii = 0; ii < 4; ++ii) {
      const int i = w * 4 + ii;
      const int vrow = i * 8 + (lane >> 3);
      gld_lds16(Vg + (size_t)vrow * 2048 + k0 + (size_t)(((lane & 7) ^ (vrow & 7)) * 8),
                &v_lds[buf][i * 512]);
    }
  };

  for (int half = 0; half < 2; ++half) {
    const int qt = half ? (31 - bx) : bx;
    const int q0 = qt * 64 + w * 16;
    bf16x8 aq[4];
    {
      const u16* qp = Q + qkb + (size_t)(q0 + l15) * 128 + lhi * 8;
#pragma unroll
      for (int ks = 0; ks < 4; ++ks) aq[ks] = *reinterpret_cast<const bf16x8*>(qp + ks * 32);
    }
    f32x4 o[8];
#pragma unroll
    for (int dt = 0; dt < 8; ++dt)
#pragma unroll
      for (int i = 0; i < 4; ++i) o[dt][i] = 0.0f;
    float mrow[4] = {-1e30f, -1e30f, -1e30f, -1e30f};
    float lrow[4] = {0.f, 0.f, 0.f, 0.f};
    const int rbase = q0 + (lhi << 2);
    const int ktmax = qt;

    __syncthreads();
    stage(0, 0);
    int cur = 0;
    for (int kt = 0; kt <= ktmax; ++kt) {
      __syncthreads();
      if (kt < ktmax) stage(cur ^ 1, (kt + 1) * 64);

      const char* kbb = (const char*)(&k_lds[cur][0]);
      f32x4 s4[4];
#pragma unroll
      for (int nt = 0; nt < 4; ++nt)
#pragma unroll
        for (int i = 0; i < 4; ++i) s4[nt][i] = 0.0f;
#pragma unroll
      for (int nt = 0; nt < 4; ++nt) {
        const int krow = nt * 16 + l15;
#pragma unroll
        for (int ks = 0; ks < 4; ++ks) {
          const bf16x8 bk = *reinterpret_cast<const bf16x8*>(
              kbb + krow * 256 + ((ks * 64 + lhi * 16) ^ kxor));
          s4[nt] = __builtin_amdgcn_mfma_f32_16x16x32_bf16(aq[ks], bk, s4[nt], 0, 0, 0);
        }
      }
      if (kt == ktmax) {
#pragma unroll
        for (int nt = 0; nt < 4; ++nt) {
          const int col = kt * 64 + nt * 16 + l15;
#pragma unroll
          for (int r = 0; r < 4; ++r)
            if (col > rbase + r) s4[nt][r] = -1e30f;
        }
      }
      float alpha[4];
#pragma unroll
      for (int r = 0; r < 4; ++r) {
        float mx = fmaxf(fmaxf(s4[0][r], s4[1][r]), fmaxf(s4[2][r], s4[3][r]));
        mx = fmaxf(mx, __shfl_xor(mx, 1));
        mx = fmaxf(mx, __shfl_xor(mx, 2));
        mx = fmaxf(mx, __shfl_xor(mx, 4));
        mx = fmaxf(mx, __shfl_xor(mx, 8));
        const float mn = fmaxf(mrow[r], mx);
        alpha[r] = __expf(mrow[r] - mn);
        mrow[r] = mn;
      }
      float ps[4] = {0.f, 0.f, 0.f, 0.f};
#pragma unroll
      for (int nt = 0; nt < 4; ++nt)
#pragma unroll
        for (int r = 0; r < 4; ++r) {
          const float p = __expf(s4[nt][r] - mrow[r]);
          ps[r] += p;
          const int prow = (lhi << 2) + r;
          const int cbyte = (nt * 16 + l15) * 2;
          *(u16*)(pw + prow * 128 + (cbyte ^ ((prow & 7) << 4))) = f2bf(p);
        }
#pragma unroll
      for (int r = 0; r < 4; ++r) {
        float rs = ps[r];
        rs += __shfl_xor(rs, 1);
        rs += __shfl_xor(rs, 2);
        rs += __shfl_xor(rs, 4);
        rs += __shfl_xor(rs, 8);
        lrow[r] = lrow[r] * alpha[r] + rs;
#pragma unroll
        for (int dt = 0; dt < 8; ++dt) o[dt][r] *= alpha[r];
      }
      const char* vbb = (const char*)(&v_lds[cur][0]);
#pragma unroll
      for (int ks2 = 0; ks2 < 2; ++ks2) {
        const bf16x8 ap = *reinterpret_cast<const bf16x8*>(
            pw + l15 * 128 + ((ks2 * 64 + (lhi << 4)) ^ kxor));
#pragma unroll
        for (int dt = 0; dt < 8; ++dt) {
          const int vrow = dt * 16 + l15;
          const bf16x8 bv = *reinterpret_cast<const bf16x8*>(
              vbb + vrow * 128 + ((ks2 * 64 + lhi * 16) ^ kxor));
          o[dt] = __builtin_amdgcn_mfma_f32_16x16x32_bf16(ap, bv, o[dt], 0, 0, 0);
        }
      }
      cur ^= 1;
    }
#pragma unroll
    for (int r = 0; r < 4; ++r) {
      const float inv = 1.0f / lrow[r];
      const int row = rbase + r;
      u16* op = O + (size_t)(bb * 2048 + row) * 2048 + h * 128 + l15;
#pragma unroll
      for (int dt = 0; dt < 8; ++dt) op[dt * 16] = f2bf(o[dt][r] * inv);
    }
  }
}

extern "C" void kernel_launch(void* const* d_in, const int* in_sizes, int n_in,
                              void* d_out, int out_size, void* d_ws, size_t ws_size,
                              hipStream_t stream) {
  const float* x = (const float*)d_in[0];      // (2,2048,2048) f32
  const float* wqkv = (const float*)d_in[1];   // (6144,2048) f32
  const float* wo = (const float*)d_in[2];     // (2048,2048) f32
  float* out = (float*)d_out;                  // (2,2048,2048) f32
  u16* ws = (u16*)d_ws;

  u16* xb = ws;                    // 8,388,608 elems
  u16* wqkvb = xb + 8388608;       // 12,582,912 (rotary-folded Q/K rows + plain V rows)
  u16* wob = wqkvb + 12582912;     // 4,194,304
  u16* Qb = wob + 4194304;         // 8,388,608
  u16* Kb = Qb + 8388608;          // 8,388,608
  u16* Vb = Kb + 8388608;          // 8,388,608  (total ~100.7 MB)
  u16* Vtb = wqkvb;                // alias: wqkvb dead after QKV GEMM
  u16* attn = xb;                  // alias: xb dead after QKV GEMM

  cvt_bf16_kernel<<<8192, 256, 0, stream>>>(x, xb, 2097152);
  rotw_kernel<<<4096, 256, 0, stream>>>(wqkv, wqkvb);
  cvt_bf16_kernel<<<4096, 256, 0, stream>>>(wqkv + (size_t)4096 * 2048,
                                            wqkvb + (size_t)4096 * 2048, 1048576);
  cvt_bf16_kernel<<<4096, 256, 0, stream>>>(wo, wob, 1048576);

  // QKV: M=4096, N=6144, K=2048 -> scatter to Q/K/V (B,H,T,dk) bf16 (rotary pre-folded)
  gemm8p_kernel<0><<<dim3(16, 24), 512, 0, stream>>>(xb, wqkvb, 2048, 0, Qb, Kb, Vb, nullptr);

  transpose_v_kernel<<<dim3(2, 32, 32), 256, 0, stream>>>(Vb, Vtb);

  attn_kernel<<<dim3(16, 32), 256, 0, stream>>>(Qb, Kb, Vtb, attn);

  // Out proj: M=4096, N=2048, K=2048 -> f32 d_out
  gemm_bt_kernel<<<dim3(32, 16), 256, 0, stream>>>(attn, wob, 2048, 2048, out);
}